// Round 11
// baseline (217.713 us; speedup 1.0000x reference)
//
#include <hip/hip_runtime.h>
#include <hip/hip_bf16.h>
#include <stdint.h>

// Problem constants
#define Bn   32
#define CIN  128
#define Hh   56
#define Ww   56
#define COUT 256
#define HP   58            // padded rows (1 top + 1 bottom)
#define WP   58            // padded width: 0=pad, 1..56 data, 57=pad
#define ROWB (WP*CIN)      // 7424 elements per padded row
#define NCHUNK 36          // K chunks of 32, order kt = hf*18 + kh*6 + kw*2 + c

// prep kernel block partition (all write-disjoint regions, single launch)
#define DATA_BLKS (Bn*Hh)                 // 1792: one (b,h) data row each
#define ZERO_BLKS (Bn)                    // 32: pad rows + side pad columns
#define WT_BLKS   96                      // (mb,hf,kh): 16*2*3 weight slabs
#define PREP_GRID (DATA_BLKS + ZERO_BLKS + WT_BLKS)

typedef __attribute__((ext_vector_type(8))) short short8;     // 8 x bf16
typedef __attribute__((ext_vector_type(4))) float floatx4;

__device__ __forceinline__ void async_copy16(const void* g, void* l) {
  // global -> LDS direct copy: GLOBAL address is PER-LANE; LDS dest =
  // wave-uniform base + lane*16.  [m104/m108]
  __builtin_amdgcn_global_load_lds(
      (const __attribute__((address_space(1))) uint32_t*)g,
      (__attribute__((address_space(3))) uint32_t*)l, 16, 0, 0);
}

__device__ __forceinline__ uint32_t pk2(float a, float b) {
  union { __hip_bfloat16 h; unsigned short u; } ca, cb;
  ca.h = __float2bfloat16(a);
  cb.h = __float2bfloat16(b);
  return (uint32_t)ca.u | ((uint32_t)cb.u << 16);
}

// ---------------------------------------------------------------------------
// prep: single launch replacing xform_x + xform_w (R1-verified, unchanged).
// ---------------------------------------------------------------------------
__global__ __launch_bounds__(256) void prep(const float* __restrict__ x,
                                            const float* __restrict__ w,
                                            __hip_bfloat16* __restrict__ xp,
                                            __hip_bfloat16* __restrict__ wtf) {
  __shared__ uint32_t t[HP * 65];   // 15080 B; weight path aliases as float[]
  const int bid = blockIdx.x, tid = threadIdx.x;

  if (bid < DATA_BLKS) {
    const int b = bid / Hh, h = bid % Hh;
    const float* xrow = x + (size_t)b * (CIN * Hh * Ww) + (size_t)h * Ww;
    for (int i = tid; i < 1024; i += 256) {
      const int wq = i & 15, cp = i >> 4;
      if (wq < 14) {
        const float* g0 = xrow + (size_t)(2 * cp) * (Hh * Ww) + wq * 4;
        const float4 v0 = *(const float4*)g0;
        const float4 v1 = *(const float4*)(g0 + Hh * Ww);
        const int r0 = (1 + 4 * wq) * 65 + cp;
        t[r0      ] = pk2(v0.x, v1.x);
        t[r0 +  65] = pk2(v0.y, v1.y);
        t[r0 + 130] = pk2(v0.z, v1.z);
        t[r0 + 195] = pk2(v0.w, v1.w);
      }
    }
    __syncthreads();
    const size_t obase = ((size_t)b * HP + (h + 1)) * ROWB;
    for (int i = tid; i < 896; i += 256) {
      const int wo = 1 + (i >> 4), cq = i & 15;
      const uint32_t* s = &t[wo * 65 + cq * 4];
      uint4 d; d.x = s[0]; d.y = s[1]; d.z = s[2]; d.w = s[3];
      *(uint4*)(xp + obase + (size_t)wo * CIN + cq * 8) = d;
    }
  } else if (bid < DATA_BLKS + ZERO_BLKS) {
    const int b = bid - DATA_BLKS;
    const uint4 z = {0u, 0u, 0u, 0u};
    uint4* r0  = (uint4*)(xp + (size_t)b * HP * ROWB);
    uint4* r57 = (uint4*)(xp + ((size_t)b * HP + (HP - 1)) * ROWB);
    for (int i = tid; i < ROWB / 8; i += 256) { r0[i] = z; r57[i] = z; }
    for (int i = tid; i < Hh * 32; i += 256) {      // 56 rows x (16+16) uint4
      const int hp = 1 + (i >> 5), s5 = i & 31;
      uint4* pr = (uint4*)(xp + ((size_t)b * HP + hp) * ROWB);
      pr[s5 < 16 ? s5 : (912 + s5 - 16)] = z;       // 912 = 57*128*2/16
    }
  } else {
    const int widx = bid - (DATA_BLKS + ZERO_BLKS);
    const int mb = widx / 6, t6 = widx % 6, hf = t6 / 3, kh = t6 % 3;
    float* s = (float*)t;                            // 3072 floats = 12 KB
    const float* wbase = w + (size_t)(mb * 16) * (CIN * 9) + hf * 576 + kh * 3;
    for (int idx = tid; idx < 3072; idx += 256) {    // s[m'][ci'][kw]
      const int mp = idx / 192, r2 = idx - mp * 192;
      const int cip = r2 / 3, p = r2 - cip * 3;
      s[idx] = wbase[(size_t)mp * (CIN * 9) + cip * 9 + p];
    }
    __syncthreads();
    uint32_t* wtfU = (uint32_t*)wtf;
    for (int k = 0; k < 6; ++k) {                    // 6 kt values: r = kw*2+c
      const int u = tid + k * 256;
      const int r = u >> 8, lane = (u >> 2) & 63, ep = u & 3;
      const int kw = r >> 1, c = r & 1;
      const int kt = hf * 18 + kh * 6 + r;
      const int fm = lane & 15, q = lane >> 4;
      const int cb = c * 32 + q * 8 + 2 * ep;        // ci' of even element
      const float v0 = s[fm * 192 + cb * 3 + kw];
      const float v1 = s[fm * 192 + (cb + 1) * 3 + kw];
      wtfU[(size_t)(kt * 16 + mb) * 256 + lane * 4 + ep] = pk2(v0, v1);
    }
  }
}

// ---------------------------------------------------------------------------
// Conv GEMM — R7 resubmit x4 (R7-R10 benches were infra timeouts):
// the CLEAN depth-2 experiment. Exact R1 skeleton (A in LDS, 4 waves,
// 128x128, one barrier/step, 3 blocks/CU) with ONLY the sync changed:
//   3 LDS buffers (48KB x 3 blocks = 144KB <= 160KB), stage tile t+2 each
//   step, wait = s_waitcnt vmcnt(4) + raw s_barrier. NO sched_barrier (R2's
//   m141-mode confound), NO setprio (m190: null on lockstep), NO other deltas.
//   Each tile's 4 loads now get TWO full steps of latency cover instead of a
//   forced vmcnt(0) drain every step.
//   Race audit: stage(t+2) writes buf[(t+2)%3], last read at step t-1; those
//   ds_reads retired (lgkmcnt) before their MFMAs, which precede barrier(t);
//   every wave passes barrier(t) before any wave's stage(t+2) executes.
//   Wait-then-barrier makes tile t globally resident (each thread's own
//   loads retired at vmcnt(4); barrier publishes). Tail: t=34 vmcnt(4)
//   (tile 35 in flight), t=35 vmcnt(0).
//   B path: T2 both-sides swizzle (R2-verified: SQ_LDS_BANK_CONFLICT = 0).
// ---------------------------------------------------------------------------
__global__ __launch_bounds__(256, 3) void conv_gemm(const __hip_bfloat16* __restrict__ wtf,
                                                    const __hip_bfloat16* __restrict__ xp,
                                                    const float* __restrict__ bias,
                                                    float* __restrict__ y) {
  __shared__ __align__(16) char Ab[3][8192];   // [buf][mb' 0..7][lane][16B]
  __shared__ __align__(16) char Bb[3][8192];   // [buf][pixel 0..127][64B swz]

  const int tid  = threadIdx.x;
  const int lane = tid & 63, wv = tid >> 6;
  const int fm = lane & 15, q = lane >> 4;
  const int waveM = wv & 1, waveN = wv >> 1;
  // T2 read-side swizzle (R2-verified, conflicts=0): 16B-unit q ^ ((fm>>1)&3)
  const int qx16 = (q ^ ((fm >> 1) & 3)) * 16;

  // XCD swizzle: gid, gid+8 share bn (same B tile) on one XCD. Bijective/1568.
  const int gid = blockIdx.x;
  const int bm = (gid >> 3) & 1;
  const int bn = (gid & 7) | ((gid >> 4) << 3);   // [0,784)
  const int m0 = bm * 128, n0 = bn * 128;

  // ---- A staging source: PER-LANE address.
  const char* aSrc = (const char*)wtf + (size_t)bm * 8192 + wv * 2048 + lane * 16;

  // ---- B staging sources: 2 pixel-groups of 16 per wave. T2 write-side:
  // swizzle the GLOBAL 16B-unit by ((lane>>3)&3); LDS dest stays linear
  // (global_load_lds requirement, m104). Same involution as the read side.
  const __hip_bfloat16* bSrc[2];
#pragma unroll
  for (int c = 0; c < 2; ++c) {
    const int sr = wv * 32 + c * 16 + (lane >> 2);     // pixel row in tile
    const int n_r = n0 + sr;
    const int b = n_r / 3136, r = n_r - b * 3136, h = r / 56, w = r - h * 56;
    const int c16 = (lane & 3) ^ ((lane >> 3) & 3);    // swizzled 16B unit
    bSrc[c] = xp + (size_t)((b * HP + h) * WP + w) * CIN + c16 * 8;
  }

  floatx4 acc[4][4];
#pragma unroll
  for (int i = 0; i < 4; ++i)
#pragma unroll
    for (int j = 0; j < 4; ++j) acc[i][j] = (floatx4){0.f, 0.f, 0.f, 0.f};

#define STAGE(KT, BUF)                                                          \
  do {                                                                          \
    const int _kt = (KT);                                                       \
    const int _rem = _kt % 18, _kh = _rem / 6, _r2 = _rem % 6;                  \
    const int _kw = _r2 >> 1, _ci0 = (_kt / 18) * 64 + (_r2 & 1) * 32;          \
    const int _bOff = (_kh * WP + _kw) * CIN + _ci0;                            \
    async_copy16(aSrc + (size_t)_kt * 16384, Ab[BUF] + wv * 2048);              \
    async_copy16(aSrc + (size_t)_kt * 16384 + 1024, Ab[BUF] + wv * 2048 + 1024);\
    async_copy16(bSrc[0] + _bOff, Bb[BUF] + wv * 2048);                         \
    async_copy16(bSrc[1] + _bOff, Bb[BUF] + wv * 2048 + 1024);                  \
  } while (0)

#define BODY(BUF)                                                               \
  do {                                                                          \
    const int _buf = (BUF);                                                     \
    short8 a[4], b[4];                                                          \
    _Pragma("unroll")                                                           \
    for (int i = 0; i < 4; ++i)                                                 \
      a[i] = *(const short8*)(Ab[_buf] + (waveM * 4 + i) * 1024 + lane * 16);   \
    _Pragma("unroll")                                                           \
    for (int j = 0; j < 4; ++j)                                                 \
      b[j] = *(const short8*)(Bb[_buf] + (waveN * 64 + j * 16 + fm) * 64 + qx16);\
    _Pragma("unroll")                                                           \
    for (int i = 0; i < 4; ++i)                                                 \
      _Pragma("unroll")                                                         \
      for (int j = 0; j < 4; ++j)                                               \
        acc[i][j] = __builtin_amdgcn_mfma_f32_16x16x32_bf16(a[i], b[j],         \
                                                            acc[i][j], 0, 0, 0);\
  } while (0)

  STAGE(0, 0);   // prologue: tiles 0,1 in flight (8 loads/thread)
  STAGE(1, 1);

#pragma unroll 3
  for (int kt = 0; kt < 34; ++kt) {      // stages tiles 2..35
    asm volatile("s_waitcnt vmcnt(4)" ::: "memory");   // own tile-kt loads done
    __builtin_amdgcn_s_barrier();                      // -> tile kt resident
    STAGE(kt + 2, (kt + 2) % 3);
    BODY(kt % 3);
  }
  {                                      // kt = 34: tile 35's 4 loads in flight
    asm volatile("s_waitcnt vmcnt(4)" ::: "memory");
    __builtin_amdgcn_s_barrier();
    BODY(1);                             // 34 % 3
  }
  {                                      // kt = 35: final drain
    asm volatile("s_waitcnt vmcnt(0)" ::: "memory");
    __builtin_amdgcn_s_barrier();
    BODY(2);                             // 35 % 3
  }
#undef BODY
#undef STAGE

  // ---- epilogue: D col = lane&15 (n), row = (lane>>4)*4 + reg (m)
  const int col = lane & 15, quad = lane >> 4;
#pragma unroll
  for (int j = 0; j < 4; ++j) {
    const int n = n0 + waveN * 64 + j * 16 + col;
    const int bb = n / 3136, nr = n - bb * 3136;
    const size_t base = (size_t)bb * (COUT * 3136) + nr;
#pragma unroll
    for (int i = 0; i < 4; ++i) {
      const int co0 = m0 + waveM * 64 + i * 16 + quad * 4;
      const floatx4 b4 = *(const floatx4*)&bias[co0];
#pragma unroll
      for (int r = 0; r < 4; ++r) {
        y[base + (size_t)(co0 + r) * 3136] = acc[i][j][r] + b4[r];
      }
    }
  }
}

extern "C" void kernel_launch(void* const* d_in, const int* in_sizes, int n_in,
                              void* d_out, int out_size, void* d_ws, size_t ws_size,
                              hipStream_t stream) {
  const float* x = (const float*)d_in[0];
  const float* w = (const float*)d_in[1];
  const float* b = (const float*)d_in[2];
  float* y = (float*)d_out;

  // ws footprint: 27,541,504 + 589,824 = 28,131,328 B — identical to prior rounds
  const size_t xpad_bytes = (size_t)Bn * HP * ROWB * sizeof(__hip_bfloat16);
  __hip_bfloat16* xp  = (__hip_bfloat16*)d_ws;
  __hip_bfloat16* wtf = (__hip_bfloat16*)((char*)d_ws + xpad_bytes);

  prep<<<PREP_GRID, 256, 0, stream>>>(x, w, xp, wtf);
  conv_gemm<<<2 * ((Bn * Hh * Ww) / 128), 256, 0, stream>>>(wtf, xp, b, y);
}

// Round 13
// 207.548 us; speedup vs baseline: 1.0490x; 1.0490x over previous
//
#include <hip/hip_runtime.h>
#include <hip/hip_bf16.h>
#include <stdint.h>

// Problem constants
#define Bn   32
#define CIN  128
#define Hh   56
#define Ww   56
#define COUT 256
#define HP   58            // padded rows (1 top + 1 bottom)
#define WP   58            // padded width: 0=pad, 1..56 data, 57=pad
#define ROWB (WP*CIN)      // 7424 elements per padded row
#define NCHUNK 36          // K chunks of 32, order kt = hf*18 + kh*6 + kw*2 + c

// prep kernel block partition (all write-disjoint regions, single launch)
#define DATA_BLKS (Bn*Hh)                 // 1792: one (b,h) data row each
#define ZERO_BLKS (Bn)                    // 32: pad rows + side pad columns
#define WT_BLKS   96                      // (mb,hf,kh): 16*2*3 weight slabs
#define PREP_GRID (DATA_BLKS + ZERO_BLKS + WT_BLKS)

typedef __attribute__((ext_vector_type(8))) short short8;     // 8 x bf16
typedef __attribute__((ext_vector_type(4))) float floatx4;

__device__ __forceinline__ void async_copy16(const void* g, void* l) {
  // global -> LDS direct copy: GLOBAL address is PER-LANE; LDS dest =
  // wave-uniform base + lane*16.  [m104/m108]
  __builtin_amdgcn_global_load_lds(
      (const __attribute__((address_space(1))) uint32_t*)g,
      (__attribute__((address_space(3))) uint32_t*)l, 16, 0, 0);
}

__device__ __forceinline__ uint32_t pk2(float a, float b) {
  union { __hip_bfloat16 h; unsigned short u; } ca, cb;
  ca.h = __float2bfloat16(a);
  cb.h = __float2bfloat16(b);
  return (uint32_t)ca.u | ((uint32_t)cb.u << 16);
}

// ---------------------------------------------------------------------------
// prep: single launch replacing xform_x + xform_w (R1-verified).
//   blocks [0,1792): x NCHW fp32 -> NHWC bf16 data cells
//   blocks [1792,1824): zero ONLY the pad cells of xp
//   blocks [1824,1920): w OIHW fp32 -> fragment-ordered wtf via LDS slab
// ---------------------------------------------------------------------------
__global__ __launch_bounds__(256) void prep(const float* __restrict__ x,
                                            const float* __restrict__ w,
                                            __hip_bfloat16* __restrict__ xp,
                                            __hip_bfloat16* __restrict__ wtf) {
  __shared__ uint32_t t[HP * 65];   // 15080 B; weight path aliases as float[]
  const int bid = blockIdx.x, tid = threadIdx.x;

  if (bid < DATA_BLKS) {
    const int b = bid / Hh, h = bid % Hh;
    const float* xrow = x + (size_t)b * (CIN * Hh * Ww) + (size_t)h * Ww;
    for (int i = tid; i < 1024; i += 256) {
      const int wq = i & 15, cp = i >> 4;
      if (wq < 14) {
        const float* g0 = xrow + (size_t)(2 * cp) * (Hh * Ww) + wq * 4;
        const float4 v0 = *(const float4*)g0;
        const float4 v1 = *(const float4*)(g0 + Hh * Ww);
        const int r0 = (1 + 4 * wq) * 65 + cp;
        t[r0      ] = pk2(v0.x, v1.x);
        t[r0 +  65] = pk2(v0.y, v1.y);
        t[r0 + 130] = pk2(v0.z, v1.z);
        t[r0 + 195] = pk2(v0.w, v1.w);
      }
    }
    __syncthreads();
    const size_t obase = ((size_t)b * HP + (h + 1)) * ROWB;
    for (int i = tid; i < 896; i += 256) {
      const int wo = 1 + (i >> 4), cq = i & 15;
      const uint32_t* s = &t[wo * 65 + cq * 4];
      uint4 d; d.x = s[0]; d.y = s[1]; d.z = s[2]; d.w = s[3];
      *(uint4*)(xp + obase + (size_t)wo * CIN + cq * 8) = d;
    }
  } else if (bid < DATA_BLKS + ZERO_BLKS) {
    const int b = bid - DATA_BLKS;
    const uint4 z = {0u, 0u, 0u, 0u};
    uint4* r0  = (uint4*)(xp + (size_t)b * HP * ROWB);
    uint4* r57 = (uint4*)(xp + ((size_t)b * HP + (HP - 1)) * ROWB);
    for (int i = tid; i < ROWB / 8; i += 256) { r0[i] = z; r57[i] = z; }
    for (int i = tid; i < Hh * 32; i += 256) {      // 56 rows x (16+16) uint4
      const int hp = 1 + (i >> 5), s5 = i & 31;
      uint4* pr = (uint4*)(xp + ((size_t)b * HP + hp) * ROWB);
      pr[s5 < 16 ? s5 : (912 + s5 - 16)] = z;       // 912 = 57*128*2/16
    }
  } else {
    const int widx = bid - (DATA_BLKS + ZERO_BLKS);
    const int mb = widx / 6, t6 = widx % 6, hf = t6 / 3, kh = t6 % 3;
    float* s = (float*)t;                            // 3072 floats = 12 KB
    const float* wbase = w + (size_t)(mb * 16) * (CIN * 9) + hf * 576 + kh * 3;
    for (int idx = tid; idx < 3072; idx += 256) {    // s[m'][ci'][kw]
      const int mp = idx / 192, r2 = idx - mp * 192;
      const int cip = r2 / 3, p = r2 - cip * 3;
      s[idx] = wbase[(size_t)mp * (CIN * 9) + cip * 9 + p];
    }
    __syncthreads();
    uint32_t* wtfU = (uint32_t*)wtf;
    for (int k = 0; k < 6; ++k) {                    // 6 kt values: r = kw*2+c
      const int u = tid + k * 256;
      const int r = u >> 8, lane = (u >> 2) & 63, ep = u & 3;
      const int kw = r >> 1, c = r & 1;
      const int kt = hf * 18 + kh * 6 + r;
      const int fm = lane & 15, q = lane >> 4;
      const int cb = c * 32 + q * 8 + 2 * ep;        // ci' of even element
      const float v0 = s[fm * 192 + cb * 3 + kw];
      const float v1 = s[fm * 192 + (cb + 1) * 3 + kw];
      wtfU[(size_t)(kt * 16 + mb) * 256 + lane * 4 + ep] = pk2(v0, v1);
    }
  }
}

// ---------------------------------------------------------------------------
// Conv GEMM — FINAL (locked-in): the R1-measured best (conv_gemm 78.5us,
// dur_us 209.4). Session evidence (R2,R4,R5,R6,R11) falsified: depth-2
// counted-vmcnt (+sched_barrier 96.4 / clean 85.9), 256x128 8-wave (84.0),
// A-in-VGPR (83.5), 5 blk/CU (80.5), T2-swizzle-timing (null at 2-phase,
// m252-consistent). Structure: 128x128 tile, 4 waves x (4x4 of 16x16x32
// bf16), BK=32, 36 iters, ONE __syncthreads per iter; stage(kt+1) issued
// before MFMA(kt). LDS 2x(8KB A + 8KB B) = 32KB; 3 blocks/CU.
// Remaining gap to the 28.5us MFMA floor requires the co-designed 8-phase
// T-stack (m201 template, exact phase placement) — out of adaptation reach
// here per three failed ports.
// ---------------------------------------------------------------------------
__global__ __launch_bounds__(256, 3) void conv_gemm(const __hip_bfloat16* __restrict__ wtf,
                                                    const __hip_bfloat16* __restrict__ xp,
                                                    const float* __restrict__ bias,
                                                    float* __restrict__ y) {
  __shared__ __align__(16) char Ab[2][8192];   // [buf][mb' 0..7][lane][16B]
  __shared__ __align__(16) char Bb[2][8192];   // [buf][pixel 0..127][64B]

  const int tid  = threadIdx.x;
  const int lane = tid & 63, wv = tid >> 6;
  const int fm = lane & 15, q = lane >> 4;
  const int waveM = wv & 1, waveN = wv >> 1;

  // XCD swizzle: gid, gid+8 share bn (same B tile) on one XCD. Bijective/1568.
  const int gid = blockIdx.x;
  const int bm = (gid >> 3) & 1;
  const int bn = (gid & 7) | ((gid >> 4) << 3);   // [0,784)
  const int m0 = bm * 128, n0 = bn * 128;

  // ---- A staging source: PER-LANE address.
  const char* aSrc = (const char*)wtf + (size_t)bm * 8192 + wv * 2048 + lane * 16;

  // ---- B staging sources: 2 pixel-groups of 16 per wave (per-lane already)
  const __hip_bfloat16* bSrc[2];
#pragma unroll
  for (int c = 0; c < 2; ++c) {
    const int sr = wv * 32 + c * 16 + (lane >> 2);     // pixel row in tile
    const int n_r = n0 + sr;
    const int b = n_r / 3136, r = n_r - b * 3136, h = r / 56, w = r - h * 56;
    bSrc[c] = xp + (size_t)((b * HP + h) * WP + w) * CIN + (lane & 3) * 8;
  }

  floatx4 acc[4][4];
#pragma unroll
  for (int i = 0; i < 4; ++i)
#pragma unroll
    for (int j = 0; j < 4; ++j) acc[i][j] = (floatx4){0.f, 0.f, 0.f, 0.f};

#define STAGE(KT, BUF)                                                          \
  do {                                                                          \
    const int _kt = (KT);                                                       \
    const int _rem = _kt % 18, _kh = _rem / 6, _r2 = _rem % 6;                  \
    const int _kw = _r2 >> 1, _ci0 = (_kt / 18) * 64 + (_r2 & 1) * 32;          \
    const int _bOff = (_kh * WP + _kw) * CIN + _ci0;                            \
    async_copy16(aSrc + (size_t)_kt * 16384, Ab[BUF] + wv * 2048);              \
    async_copy16(aSrc + (size_t)_kt * 16384 + 1024, Ab[BUF] + wv * 2048 + 1024);\
    async_copy16(bSrc[0] + _bOff, Bb[BUF] + wv * 2048);                         \
    async_copy16(bSrc[1] + _bOff, Bb[BUF] + wv * 2048 + 1024);                  \
  } while (0)

  STAGE(0, 0);   // prologue

#pragma unroll 2
  for (int kt = 0; kt < NCHUNK; ++kt) {
    const int buf = kt & 1;
    __syncthreads();                 // buffer `buf` ready; prior reads done
    if (kt + 1 < NCHUNK) STAGE(kt + 1, buf ^ 1);   // fire-and-forget for next iter

    short8 a[4], b[4];
#pragma unroll
    for (int i = 0; i < 4; ++i)
      a[i] = *(const short8*)(Ab[buf] + (waveM * 4 + i) * 1024 + lane * 16);
#pragma unroll
    for (int j = 0; j < 4; ++j)
      b[j] = *(const short8*)(Bb[buf] + (waveN * 64 + j * 16 + fm) * 64 + q * 16);
#pragma unroll
    for (int i = 0; i < 4; ++i)
#pragma unroll
      for (int j = 0; j < 4; ++j)
        acc[i][j] = __builtin_amdgcn_mfma_f32_16x16x32_bf16(a[i], b[j], acc[i][j], 0, 0, 0);
  }
#undef STAGE

  // ---- epilogue: D col = lane&15 (n), row = (lane>>4)*4 + reg (m)
  const int col = lane & 15, quad = lane >> 4;
#pragma unroll
  for (int j = 0; j < 4; ++j) {
    const int n = n0 + waveN * 64 + j * 16 + col;
    const int bb = n / 3136, nr = n - bb * 3136;
    const size_t base = (size_t)bb * (COUT * 3136) + nr;
#pragma unroll
    for (int i = 0; i < 4; ++i) {
      const int co0 = m0 + waveM * 64 + i * 16 + quad * 4;
      const floatx4 b4 = *(const floatx4*)&bias[co0];
#pragma unroll
      for (int r = 0; r < 4; ++r) {
        y[base + (size_t)(co0 + r) * 3136] = acc[i][j][r] + b4[r];
      }
    }
  }
}

extern "C" void kernel_launch(void* const* d_in, const int* in_sizes, int n_in,
                              void* d_out, int out_size, void* d_ws, size_t ws_size,
                              hipStream_t stream) {
  const float* x = (const float*)d_in[0];
  const float* w = (const float*)d_in[1];
  const float* b = (const float*)d_in[2];
  float* y = (float*)d_out;

  // ws footprint: 27,541,504 + 589,824 = 28,131,328 B — identical to prior rounds
  const size_t xpad_bytes = (size_t)Bn * HP * ROWB * sizeof(__hip_bfloat16);
  __hip_bfloat16* xp  = (__hip_bfloat16*)d_ws;
  __hip_bfloat16* wtf = (__hip_bfloat16*)((char*)d_ws + xpad_bytes);

  prep<<<PREP_GRID, 256, 0, stream>>>(x, w, xp, wtf);
  conv_gemm<<<2 * ((Bn * Hh * Ww) / 128), 256, 0, stream>>>(wtf, xp, b, y);
}